// Round 1
// baseline (3021.234 us; speedup 1.0000x reference)
//
#include <hip/hip_runtime.h>
#include <hip/hip_bf16.h>
#include <cstddef>

// ---------------------------------------------------------------------------
// MORP: Lu = irfft( g(k) * rfft( h(u) ) ), h/g tiny MLPs (1->64->64->{1,2}, ELU)
// B=2048 rows, N=8192, M=4097, W=64.
// Plan: kernel1 computes g(k) -> ws (4097 cpx). kernel2: one block per row:
//   phase 1: per-element h-MLP (w2 staged in LDS, fp32 vector ALU)
//   phase 2: packed complex FFT-4096 in LDS (3 x radix-16, self-sorting)
//   phase 3: rfft unpack + spectral multiply + irfft repack (fused, per-k)
//   phase 4: inverse FFT-4096, unpack, scaled write.
// ---------------------------------------------------------------------------

#define PI_F 3.14159265358979323846f
#define TWO_PI_F 6.28318530717958647693f

struct __align__(8) cpx { float x, y; };

__device__ __forceinline__ cpx cmul(cpx a, cpx b) {
    return cpx{fmaf(a.x, b.x, -a.y * b.y), fmaf(a.x, b.y, a.y * b.x)};
}
__device__ __forceinline__ cpx cadd(cpx a, cpx b) { return cpx{a.x + b.x, a.y + b.y}; }
__device__ __forceinline__ cpx csub(cpx a, cpx b) { return cpx{a.x - b.x, a.y - b.y}; }
__device__ __forceinline__ cpx cscale(float s, cpx a) { return cpx{s * a.x, s * a.y}; }
__device__ __forceinline__ cpx cconj(cpx a) { return cpx{a.x, -a.y}; }
// multiply by (S<0 ? -i : +i)
template <int S>
__device__ __forceinline__ cpx crot(cpx z) {
    return (S < 0) ? cpx{z.y, -z.x} : cpx{-z.y, z.x};
}

__device__ __forceinline__ float elu(float x) {
    return x > 0.0f ? x : (__expf(x) - 1.0f);
}

// LDS index swizzle: XOR mid/hi digits into the low digit so that strides of
// 1, 16 and 256 (cpx elements) all spread uniformly over the 32 banks.
__device__ __forceinline__ int swz(int i) {
    return i ^ (((i >> 4) ^ (i >> 8)) & 15);
}

// ---------------------------------------------------------------------------
// In-register 16-point DFT (natural order in/out), sign S (-1 fwd, +1 inv).
// 16 = 4x4 Cooley-Tukey.
// ---------------------------------------------------------------------------
template <int S>
__device__ __forceinline__ void dft16(cpx v[16]) {
    cpx f[16];
#pragma unroll
    for (int a = 0; a < 4; ++a) {
        cpx x0 = v[a], x1 = v[a + 4], x2 = v[a + 8], x3 = v[a + 12];
        cpx e0 = cadd(x0, x2), e1 = csub(x0, x2);
        cpx o0 = cadd(x1, x3), o1 = crot<S>(csub(x1, x3));
        f[a * 4 + 0] = cadd(e0, o0);
        f[a * 4 + 1] = cadd(e1, o1);
        f[a * 4 + 2] = csub(e0, o0);
        f[a * 4 + 3] = csub(e1, o1);
    }
    // twiddle w16^{S*a*c}; m = a*c in {1,2,3,4,6,9}
    constexpr float wc[10] = {1.0f, 0.92387953251128676f, 0.70710678118654752f,
                              0.38268343236508977f, 0.0f, 0.0f,
                              -0.70710678118654752f, 0.0f, 0.0f,
                              -0.92387953251128676f};
    constexpr float wsn[10] = {0.0f, 0.38268343236508977f, 0.70710678118654752f,
                               0.92387953251128676f, 1.0f, 0.0f,
                               0.70710678118654752f, 0.0f, 0.0f,
                               -0.38268343236508977f};
#pragma unroll
    for (int a = 1; a < 4; ++a) {
#pragma unroll
        for (int c = 1; c < 4; ++c) {
            const int m = a * c;
            cpx w{wc[m], (S < 0) ? -wsn[m] : wsn[m]};
            f[a * 4 + c] = cmul(f[a * 4 + c], w);
        }
    }
#pragma unroll
    for (int c = 0; c < 4; ++c) {
        cpx x0 = f[c], x1 = f[4 + c], x2 = f[8 + c], x3 = f[12 + c];
        cpx e0 = cadd(x0, x2), e1 = csub(x0, x2);
        cpx o0 = cadd(x1, x3), o1 = crot<S>(csub(x1, x3));
        v[c + 0] = cadd(e0, o0);
        v[c + 4] = cadd(e1, o1);
        v[c + 8] = csub(e0, o0);
        v[c + 12] = csub(e1, o1);
    }
}

// ---------------------------------------------------------------------------
// One stage of the 4096-point FFT (4096 = 16^3), 256 threads, self-sorting.
//   X[k3+16k2+256k1] = sum_{t1} w4096^{t1(k3+16k2+256k1)}
//                      sum_{t2} w256^{t2(k3+16k2)}
//                      sum_{t3} w16^{t3 k3} x[t1+16t2+256t3]
// STAGE 0: DFT16 over t3 (no twiddle)        idx = tid + 256*t
// STAGE 1: tw w256^{t2*k3}, DFT16 over t2    idx = t1 + 16*t + 256*k3
// STAGE 2: tw w4096^{t1*(k3+16k2)}, DFT16 over t1; scatter to k3+16k2+256k1
// ---------------------------------------------------------------------------
template <int S, int STAGE>
__device__ void fft_stage(const cpx* __restrict__ src, cpx* __restrict__ dst, int tid) {
    cpx v[16];
    if constexpr (STAGE == 0) {
#pragma unroll
        for (int t = 0; t < 16; ++t) v[t] = src[swz(tid + 256 * t)];
        dft16<S>(v);
#pragma unroll
        for (int t = 0; t < 16; ++t) dst[swz(tid + 256 * t)] = v[t];
    } else if constexpr (STAGE == 1) {
        const int t1 = tid & 15, k3 = tid >> 4;
#pragma unroll
        for (int t = 0; t < 16; ++t) v[t] = src[swz(t1 + 16 * t + 256 * k3)];
        float ang = (float)S * (TWO_PI_F / 256.0f) * (float)k3;
        cpx step;
        __sincosf(ang, &step.y, &step.x);
        cpx tw{1.0f, 0.0f};
#pragma unroll
        for (int t = 1; t < 16; ++t) {
            tw = cmul(tw, step);
            v[t] = cmul(v[t], tw);
        }
        dft16<S>(v);
#pragma unroll
        for (int t = 0; t < 16; ++t) dst[swz(t1 + 16 * t + 256 * k3)] = v[t];
    } else {
        const int k2 = tid & 15, k3 = tid >> 4;
#pragma unroll
        for (int t = 0; t < 16; ++t) v[t] = src[swz(t + 16 * k2 + 256 * k3)];
        float ang = (float)S * (TWO_PI_F / 4096.0f) * (float)(k3 + 16 * k2);
        cpx step;
        __sincosf(ang, &step.y, &step.x);
        cpx tw{1.0f, 0.0f};
#pragma unroll
        for (int t = 1; t < 16; ++t) {
            tw = cmul(tw, step);
            v[t] = cmul(v[t], tw);
        }
        dft16<S>(v);
#pragma unroll
        for (int t = 0; t < 16; ++t) dst[swz(k3 + 16 * k2 + 256 * t)] = v[t];
    }
}

// ---------------------------------------------------------------------------
// Kernel 1: gk[k] = complex MLP g(k), k = 0..4096
// ---------------------------------------------------------------------------
__global__ __launch_bounds__(256, 2) void gk_kernel(
    const float* __restrict__ kin, const float* __restrict__ gw1,
    const float* __restrict__ gb1, const float* __restrict__ gw2,
    const float* __restrict__ gb2, const float* __restrict__ gw3,
    const float* __restrict__ gb3, cpx* __restrict__ gk_out) {
    __shared__ __align__(16) float w2[4096];
    __shared__ float w1[64], b1[64], b2[64], w3r[64], w3i[64];
    __shared__ float b3r, b3i;
    const int tid = threadIdx.x;
    for (int i = tid; i < 4096; i += 256) w2[i] = gw2[i];
    if (tid < 64) {
        w1[tid] = gw1[tid];
        b1[tid] = gb1[tid];
        b2[tid] = gb2[tid];
        w3r[tid] = gw3[tid * 2 + 0];
        w3i[tid] = gw3[tid * 2 + 1];
    }
    if (tid == 0) { b3r = gb3[0]; b3i = gb3[1]; }
    __syncthreads();
    const int k = blockIdx.x * 256 + tid;
    if (k >= 4097) return;
    const float x = kin[k];
    float acc[64];
#pragma unroll
    for (int i = 0; i < 64; ++i) acc[i] = b2[i];
#pragma unroll 2
    for (int j = 0; j < 64; ++j) {
        float h1 = elu(fmaf(x, w1[j], b1[j]));
        const float4* wr = (const float4*)&w2[j * 64];
#pragma unroll
        for (int q = 0; q < 16; ++q) {
            float4 wv = wr[q];
            acc[q * 4 + 0] = fmaf(h1, wv.x, acc[q * 4 + 0]);
            acc[q * 4 + 1] = fmaf(h1, wv.y, acc[q * 4 + 1]);
            acc[q * 4 + 2] = fmaf(h1, wv.z, acc[q * 4 + 2]);
            acc[q * 4 + 3] = fmaf(h1, wv.w, acc[q * 4 + 3]);
        }
    }
    float gr = b3r, gi = b3i;
#pragma unroll
    for (int i = 0; i < 64; ++i) {
        float h2 = elu(acc[i]);
        gr = fmaf(h2, w3r[i], gr);
        gi = fmaf(h2, w3i[i], gi);
    }
    gk_out[k] = cpx{gr, gi};
}

// ---------------------------------------------------------------------------
// Kernel 2: one block per row. MLP -> FFT -> spectral -> IFFT -> write.
// ---------------------------------------------------------------------------
__global__ __launch_bounds__(256, 2) void morp_main(
    const float* __restrict__ u, const float* __restrict__ hw1,
    const float* __restrict__ hb1, const float* __restrict__ hw2,
    const float* __restrict__ hb2, const float* __restrict__ hw3,
    const float* __restrict__ hb3, const cpx* __restrict__ gk,
    float* __restrict__ out) {
    __shared__ __align__(16) cpx bufA[4096];
    __shared__ __align__(16) cpx bufB[4096];
    __shared__ float w1[64], b1[64], b2[64], w3[64];
    __shared__ float b3s;
    const int tid = threadIdx.x;
    const int row = blockIdx.x;

    // stage h weights; w2 parked in bufA (dead until FFT stage 0 writes it)
    float* w2 = (float*)bufA;
    for (int i = tid; i < 4096; i += 256) w2[i] = hw2[i];
    if (tid < 64) {
        w1[tid] = hw1[tid];
        b1[tid] = hb1[tid];
        b2[tid] = hb2[tid];
        w3[tid] = hw3[tid];
    }
    if (tid == 0) b3s = hb3[0];
    __syncthreads();

    // ---------------- phase 1: h-MLP, pack hu into bufB as z[n] = hu[2n]+i hu[2n+1]
    const float* urow = u + (size_t)row * 8192;
    float* fb = (float*)bufB;
#pragma unroll 1
    for (int grp = 0; grp < 8; ++grp) {
        const float x0 = urow[(grp * 4 + 0) * 256 + tid];
        const float x1 = urow[(grp * 4 + 1) * 256 + tid];
        const float x2 = urow[(grp * 4 + 2) * 256 + tid];
        const float x3 = urow[(grp * 4 + 3) * 256 + tid];
        float o0 = b3s, o1 = b3s, o2 = b3s, o3 = b3s;
#pragma unroll 1
        for (int pass = 0; pass < 2; ++pass) {
            float a0[32], a1[32], a2[32], a3[32];
#pragma unroll
            for (int i = 0; i < 32; ++i) {
                const float b = b2[pass * 32 + i];
                a0[i] = b; a1[i] = b; a2[i] = b; a3[i] = b;
            }
#pragma unroll 2
            for (int j = 0; j < 64; ++j) {
                const float w1j = w1[j], b1j = b1[j];
                const float h0 = elu(fmaf(x0, w1j, b1j));
                const float h1 = elu(fmaf(x1, w1j, b1j));
                const float h2 = elu(fmaf(x2, w1j, b1j));
                const float h3 = elu(fmaf(x3, w1j, b1j));
                const float4* wr = (const float4*)&w2[j * 64 + pass * 32];
#pragma unroll
                for (int q = 0; q < 8; ++q) {
                    const float4 wv = wr[q];
                    a0[q * 4 + 0] = fmaf(h0, wv.x, a0[q * 4 + 0]);
                    a0[q * 4 + 1] = fmaf(h0, wv.y, a0[q * 4 + 1]);
                    a0[q * 4 + 2] = fmaf(h0, wv.z, a0[q * 4 + 2]);
                    a0[q * 4 + 3] = fmaf(h0, wv.w, a0[q * 4 + 3]);
                    a1[q * 4 + 0] = fmaf(h1, wv.x, a1[q * 4 + 0]);
                    a1[q * 4 + 1] = fmaf(h1, wv.y, a1[q * 4 + 1]);
                    a1[q * 4 + 2] = fmaf(h1, wv.z, a1[q * 4 + 2]);
                    a1[q * 4 + 3] = fmaf(h1, wv.w, a1[q * 4 + 3]);
                    a2[q * 4 + 0] = fmaf(h2, wv.x, a2[q * 4 + 0]);
                    a2[q * 4 + 1] = fmaf(h2, wv.y, a2[q * 4 + 1]);
                    a2[q * 4 + 2] = fmaf(h2, wv.z, a2[q * 4 + 2]);
                    a2[q * 4 + 3] = fmaf(h2, wv.w, a2[q * 4 + 3]);
                    a3[q * 4 + 0] = fmaf(h3, wv.x, a3[q * 4 + 0]);
                    a3[q * 4 + 1] = fmaf(h3, wv.y, a3[q * 4 + 1]);
                    a3[q * 4 + 2] = fmaf(h3, wv.z, a3[q * 4 + 2]);
                    a3[q * 4 + 3] = fmaf(h3, wv.w, a3[q * 4 + 3]);
                }
            }
#pragma unroll
            for (int i = 0; i < 32; ++i) {
                const float w3v = w3[pass * 32 + i];
                o0 = fmaf(elu(a0[i]), w3v, o0);
                o1 = fmaf(elu(a1[i]), w3v, o1);
                o2 = fmaf(elu(a2[i]), w3v, o2);
                o3 = fmaf(elu(a3[i]), w3v, o3);
            }
        }
        const int e0 = (grp * 4 + 0) * 256 + tid;
        const int e1 = (grp * 4 + 1) * 256 + tid;
        const int e2 = (grp * 4 + 2) * 256 + tid;
        const int e3 = (grp * 4 + 3) * 256 + tid;
        fb[2 * swz(e0 >> 1) + (e0 & 1)] = o0;
        fb[2 * swz(e1 >> 1) + (e1 & 1)] = o1;
        fb[2 * swz(e2 >> 1) + (e2 & 1)] = o2;
        fb[2 * swz(e3 >> 1) + (e3 & 1)] = o3;
    }
    __syncthreads();

    // ---------------- phase 2: forward FFT-4096 of packed z, result -> bufA
    fft_stage<-1, 0>(bufB, bufA, tid);
    __syncthreads();
    fft_stage<-1, 1>(bufA, bufB, tid);
    __syncthreads();
    fft_stage<-1, 2>(bufB, bufA, tid);
    __syncthreads();

    // ---------------- phase 3: rfft unpack, multiply by g, irfft repack -> bufB
    {
        cpx w;
        {
            float ang = -TWO_PI_F * (float)tid / 8192.0f;
            __sincosf(ang, &w.y, &w.x);
        }
        const cpx wstep{0.98078528040323044913f, -0.19509032201612826785f};  // cis(-pi/16)
#pragma unroll 1
        for (int c = 0; c < 16; ++c) {
            const int k = tid + 256 * c;
            const int kk = (4096 - k) & 4095;
            const cpx Zk = bufA[swz(k)];
            const cpx Zc = cconj(bufA[swz(kk)]);  // conj(Z[N2-k])
            // huh[k] = 0.5(Zk + Zc) - 0.5 i w (Zk - Zc)
            const cpx s = cadd(Zk, Zc);
            const cpx d = csub(Zk, Zc);
            const cpx wd = cmul(w, d);
            const cpx huh{0.5f * (s.x + wd.y), 0.5f * (s.y - wd.x)};
            // huh[N2-k]: Zr = Z[N2-k] = conj(Zc), w_r = -conj(w)
            const cpx Zr = cconj(Zc);
            const cpx Zkc = cconj(Zk);
            const cpx s2 = cadd(Zr, Zkc);
            const cpx d2 = csub(Zr, Zkc);
            const cpx wr{-w.x, w.y};
            const cpx wd2 = cmul(wr, d2);
            const cpx huhr{0.5f * (s2.x + wd2.y), 0.5f * (s2.y - wd2.x)};
            // Y = g*huh; even/odd split; Zi = E + i*O
            const cpx Yk = cmul(gk[k], huh);
            const cpx Yrc = cconj(cmul(gk[4096 - k], huhr));
            const cpx E = cscale(0.5f, cadd(Yk, Yrc));
            const cpx D = cscale(0.5f, csub(Yk, Yrc));
            const cpx O = cmul(cconj(w), D);
            const cpx Zi{E.x - O.y, E.y + O.x};
            bufB[swz(k)] = Zi;
            w = cmul(w, wstep);
        }
    }
    __syncthreads();

    // ---------------- phase 4: inverse FFT-4096 (unnormalized), result -> bufA
    fft_stage<1, 0>(bufB, bufA, tid);
    __syncthreads();
    fft_stage<1, 1>(bufA, bufB, tid);
    __syncthreads();
    fft_stage<1, 2>(bufB, bufA, tid);
    __syncthreads();

    // ---------------- phase 5: unpack, scale by 1/4096, write
    const float invn = 1.0f / 4096.0f;
    cpx* orow = (cpx*)(out + (size_t)row * 8192);
#pragma unroll 1
    for (int c = 0; c < 16; ++c) {
        const int n = tid + 256 * c;
        const cpx z = bufA[swz(n)];
        orow[n] = cpx{z.x * invn, z.y * invn};
    }
}

extern "C" void kernel_launch(void* const* d_in, const int* in_sizes, int n_in,
                              void* d_out, int out_size, void* d_ws, size_t ws_size,
                              hipStream_t stream) {
    const float* u   = (const float*)d_in[0];
    const float* kin = (const float*)d_in[1];
    const float* hw1 = (const float*)d_in[2];
    const float* hb1 = (const float*)d_in[3];
    const float* hw2 = (const float*)d_in[4];
    const float* hb2 = (const float*)d_in[5];
    const float* hw3 = (const float*)d_in[6];
    const float* hb3 = (const float*)d_in[7];
    const float* gw1 = (const float*)d_in[8];
    const float* gb1 = (const float*)d_in[9];
    const float* gw2 = (const float*)d_in[10];
    const float* gb2 = (const float*)d_in[11];
    const float* gw3 = (const float*)d_in[12];
    const float* gb3 = (const float*)d_in[13];

    cpx* gk = (cpx*)d_ws;  // 4097 * 8 bytes
    gk_kernel<<<17, 256, 0, stream>>>(kin, gw1, gb1, gw2, gb2, gw3, gb3, gk);
    morp_main<<<2048, 256, 0, stream>>>(u, hw1, hb1, hw2, hb2, hw3, hb3, gk,
                                        (float*)d_out);
}

// Round 2
// 624.338 us; speedup vs baseline: 4.8391x; 4.8391x over previous
//
#include <hip/hip_runtime.h>
#include <hip/hip_bf16.h>
#include <cstddef>

// ---------------------------------------------------------------------------
// MORP: Lu = irfft( g(k) * rfft( h(u) ) ), h/g tiny MLPs (1->64->64->{1,2}, ELU)
// B=2048 rows, N=8192, M=4097, W=64.
// Round 2: h-MLP middle layer (64x64, 97% of MACs) on MFMA bf16 w/ fp32 accum.
//   - W2 fragments live in VGPRs (8 frags), b2 folded into MFMA C operand
//   - L1 (1->64) + ELU computed per-lane directly in A-fragment layout
//   - L3 (64->1) as per-lane partial dot + 4-step shfl_xor butterfly
// FFT pipeline unchanged from round 1 (packed real FFT-4096, 3x radix-16).
// ---------------------------------------------------------------------------

#define PI_F 3.14159265358979323846f
#define TWO_PI_F 6.28318530717958647693f

struct __align__(8) cpx { float x, y; };

typedef __attribute__((ext_vector_type(8))) short bf16x8v;  // 8 bf16 (4 VGPRs)
typedef __attribute__((ext_vector_type(4))) float f32x4;

__device__ __forceinline__ cpx cmul(cpx a, cpx b) {
    return cpx{fmaf(a.x, b.x, -a.y * b.y), fmaf(a.x, b.y, a.y * b.x)};
}
__device__ __forceinline__ cpx cadd(cpx a, cpx b) { return cpx{a.x + b.x, a.y + b.y}; }
__device__ __forceinline__ cpx csub(cpx a, cpx b) { return cpx{a.x - b.x, a.y - b.y}; }
__device__ __forceinline__ cpx cscale(float s, cpx a) { return cpx{s * a.x, s * a.y}; }
__device__ __forceinline__ cpx cconj(cpx a) { return cpx{a.x, -a.y}; }
template <int S>
__device__ __forceinline__ cpx crot(cpx z) {
    return (S < 0) ? cpx{z.y, -z.x} : cpx{-z.y, z.x};
}

__device__ __forceinline__ float elu(float x) {
    return x > 0.0f ? x : (__expf(x) - 1.0f);
}

__device__ __forceinline__ short f2bf_bits(float x) {
    return (short)__bfloat16_as_ushort(__float2bfloat16(x));
}

// LDS index swizzle: XOR mid/hi digits into the low digit so that strides of
// 1, 16 and 256 (cpx elements) all spread uniformly over the 32 banks.
__device__ __forceinline__ int swz(int i) {
    return i ^ (((i >> 4) ^ (i >> 8)) & 15);
}

// ---------------------------------------------------------------------------
// In-register 16-point DFT (natural order in/out), sign S (-1 fwd, +1 inv).
// ---------------------------------------------------------------------------
template <int S>
__device__ __forceinline__ void dft16(cpx v[16]) {
    cpx f[16];
#pragma unroll
    for (int a = 0; a < 4; ++a) {
        cpx x0 = v[a], x1 = v[a + 4], x2 = v[a + 8], x3 = v[a + 12];
        cpx e0 = cadd(x0, x2), e1 = csub(x0, x2);
        cpx o0 = cadd(x1, x3), o1 = crot<S>(csub(x1, x3));
        f[a * 4 + 0] = cadd(e0, o0);
        f[a * 4 + 1] = cadd(e1, o1);
        f[a * 4 + 2] = csub(e0, o0);
        f[a * 4 + 3] = csub(e1, o1);
    }
    constexpr float wc[10] = {1.0f, 0.92387953251128676f, 0.70710678118654752f,
                              0.38268343236508977f, 0.0f, 0.0f,
                              -0.70710678118654752f, 0.0f, 0.0f,
                              -0.92387953251128676f};
    constexpr float wsn[10] = {0.0f, 0.38268343236508977f, 0.70710678118654752f,
                               0.92387953251128676f, 1.0f, 0.0f,
                               0.70710678118654752f, 0.0f, 0.0f,
                               -0.38268343236508977f};
#pragma unroll
    for (int a = 1; a < 4; ++a) {
#pragma unroll
        for (int c = 1; c < 4; ++c) {
            const int m = a * c;
            cpx w{wc[m], (S < 0) ? -wsn[m] : wsn[m]};
            f[a * 4 + c] = cmul(f[a * 4 + c], w);
        }
    }
#pragma unroll
    for (int c = 0; c < 4; ++c) {
        cpx x0 = f[c], x1 = f[4 + c], x2 = f[8 + c], x3 = f[12 + c];
        cpx e0 = cadd(x0, x2), e1 = csub(x0, x2);
        cpx o0 = cadd(x1, x3), o1 = crot<S>(csub(x1, x3));
        v[c + 0] = cadd(e0, o0);
        v[c + 4] = cadd(e1, o1);
        v[c + 8] = csub(e0, o0);
        v[c + 12] = csub(e1, o1);
    }
}

// ---------------------------------------------------------------------------
// One stage of the 4096-point FFT (4096 = 16^3), 256 threads, self-sorting.
// ---------------------------------------------------------------------------
template <int S, int STAGE>
__device__ void fft_stage(const cpx* __restrict__ src, cpx* __restrict__ dst, int tid) {
    cpx v[16];
    if constexpr (STAGE == 0) {
#pragma unroll
        for (int t = 0; t < 16; ++t) v[t] = src[swz(tid + 256 * t)];
        dft16<S>(v);
#pragma unroll
        for (int t = 0; t < 16; ++t) dst[swz(tid + 256 * t)] = v[t];
    } else if constexpr (STAGE == 1) {
        const int t1 = tid & 15, k3 = tid >> 4;
#pragma unroll
        for (int t = 0; t < 16; ++t) v[t] = src[swz(t1 + 16 * t + 256 * k3)];
        float ang = (float)S * (TWO_PI_F / 256.0f) * (float)k3;
        cpx step;
        __sincosf(ang, &step.y, &step.x);
        cpx tw{1.0f, 0.0f};
#pragma unroll
        for (int t = 1; t < 16; ++t) {
            tw = cmul(tw, step);
            v[t] = cmul(v[t], tw);
        }
        dft16<S>(v);
#pragma unroll
        for (int t = 0; t < 16; ++t) dst[swz(t1 + 16 * t + 256 * k3)] = v[t];
    } else {
        const int k2 = tid & 15, k3 = tid >> 4;
#pragma unroll
        for (int t = 0; t < 16; ++t) v[t] = src[swz(t + 16 * k2 + 256 * k3)];
        float ang = (float)S * (TWO_PI_F / 4096.0f) * (float)(k3 + 16 * k2);
        cpx step;
        __sincosf(ang, &step.y, &step.x);
        cpx tw{1.0f, 0.0f};
#pragma unroll
        for (int t = 1; t < 16; ++t) {
            tw = cmul(tw, step);
            v[t] = cmul(v[t], tw);
        }
        dft16<S>(v);
#pragma unroll
        for (int t = 0; t < 16; ++t) dst[swz(k3 + 16 * k2 + 256 * t)] = v[t];
    }
}

// ---------------------------------------------------------------------------
// Kernel 1: gk[k] = complex MLP g(k), k = 0..4096  (unchanged, negligible)
// ---------------------------------------------------------------------------
__global__ __launch_bounds__(256, 2) void gk_kernel(
    const float* __restrict__ kin, const float* __restrict__ gw1,
    const float* __restrict__ gb1, const float* __restrict__ gw2,
    const float* __restrict__ gb2, const float* __restrict__ gw3,
    const float* __restrict__ gb3, cpx* __restrict__ gk_out) {
    __shared__ __align__(16) float w2[4096];
    __shared__ float w1[64], b1[64], b2[64], w3r[64], w3i[64];
    __shared__ float b3r, b3i;
    const int tid = threadIdx.x;
    for (int i = tid; i < 4096; i += 256) w2[i] = gw2[i];
    if (tid < 64) {
        w1[tid] = gw1[tid];
        b1[tid] = gb1[tid];
        b2[tid] = gb2[tid];
        w3r[tid] = gw3[tid * 2 + 0];
        w3i[tid] = gw3[tid * 2 + 1];
    }
    if (tid == 0) { b3r = gb3[0]; b3i = gb3[1]; }
    __syncthreads();
    const int k = blockIdx.x * 256 + tid;
    if (k >= 4097) return;
    const float x = kin[k];
    float acc[64];
#pragma unroll
    for (int i = 0; i < 64; ++i) acc[i] = b2[i];
#pragma unroll 2
    for (int j = 0; j < 64; ++j) {
        float h1 = elu(fmaf(x, w1[j], b1[j]));
        const float4* wr = (const float4*)&w2[j * 64];
#pragma unroll
        for (int q = 0; q < 16; ++q) {
            float4 wv = wr[q];
            acc[q * 4 + 0] = fmaf(h1, wv.x, acc[q * 4 + 0]);
            acc[q * 4 + 1] = fmaf(h1, wv.y, acc[q * 4 + 1]);
            acc[q * 4 + 2] = fmaf(h1, wv.z, acc[q * 4 + 2]);
            acc[q * 4 + 3] = fmaf(h1, wv.w, acc[q * 4 + 3]);
        }
    }
    float gr = b3r, gi = b3i;
#pragma unroll
    for (int i = 0; i < 64; ++i) {
        float h2 = elu(acc[i]);
        gr = fmaf(h2, w3r[i], gr);
        gi = fmaf(h2, w3i[i], gi);
    }
    gk_out[k] = cpx{gr, gi};
}

// ---------------------------------------------------------------------------
// Kernel 2: one block per row. MFMA-MLP -> FFT -> spectral -> IFFT -> write.
// ---------------------------------------------------------------------------
__global__ __launch_bounds__(256, 2) void morp_main(
    const float* __restrict__ u, const float* __restrict__ hw1,
    const float* __restrict__ hb1, const float* __restrict__ hw2,
    const float* __restrict__ hb2, const float* __restrict__ hw3,
    const float* __restrict__ hb3, const cpx* __restrict__ gk,
    float* __restrict__ out) {
    __shared__ __align__(16) cpx bufA[4096];
    __shared__ __align__(16) cpx bufB[4096];
    const int tid = threadIdx.x;
    const int row = blockIdx.x;
    const int lane = tid & 63;
    const int wid = tid >> 6;       // 4 waves per block
    const int lg = lane >> 4;       // k-group (A/B operands), row-group (D)
    const int li = lane & 15;       // element index (A rows), col index (B/D)

    // ---------------- preload MLP parameters into registers (one-time)
    // W2 fragments: B[k][n] = w2[k][n]; lane holds B[lg*8+j + 32*half][nt*16+li]
    bf16x8v w2f[4][2];
#pragma unroll
    for (int nt = 0; nt < 4; ++nt) {
#pragma unroll
        for (int h = 0; h < 2; ++h) {
            bf16x8v f;
#pragma unroll
            for (int j = 0; j < 8; ++j)
                f[j] = f2bf_bits(hw2[(32 * h + lg * 8 + j) * 64 + nt * 16 + li]);
            w2f[nt][h] = f;
        }
    }
    // L1 weights in A-fragment k order: k = lg*8 + j + 32*half
    float w1v[16], b1v[16];
#pragma unroll
    for (int h = 0; h < 2; ++h) {
#pragma unroll
        for (int j = 0; j < 8; ++j) {
            w1v[h * 8 + j] = hw1[32 * h + lg * 8 + j];
            b1v[h * 8 + j] = hb1[32 * h + lg * 8 + j];
        }
    }
    // b2 as MFMA C-fragment (col-dependent only), w3 per D-col
    f32x4 cinit[4];
    float w3v[4];
#pragma unroll
    for (int nt = 0; nt < 4; ++nt) {
        const float bv = hb2[nt * 16 + li];
        cinit[nt] = f32x4{bv, bv, bv, bv};
        w3v[nt] = hw3[nt * 16 + li];
    }
    const float b3v = hb3[0];

    // ---------------- phase 1: h-MLP via MFMA, pack hu into bufB (packed cpx)
    const float* urow = u + (size_t)row * 8192;
    float* fb = (float*)bufB;
#pragma unroll 1
    for (int it = 0; it < 32; ++it) {
        const int base = it * 256 + wid * 64;
        // two 16-element sub-tiles per iteration to amortize loop overhead
#pragma unroll
        for (int sub = 0; sub < 4; ++sub) {
            const int eb = base + sub * 16;
            const float uv = urow[eb + li];
            bf16x8v af0, af1;
#pragma unroll
            for (int j = 0; j < 8; ++j) {
                const float x0 = fmaf(uv, w1v[j], b1v[j]);
                af0[j] = f2bf_bits(elu(x0));
                const float x1 = fmaf(uv, w1v[8 + j], b1v[8 + j]);
                af1[j] = f2bf_bits(elu(x1));
            }
            f32x4 acc0 = __builtin_amdgcn_mfma_f32_16x16x32_bf16(af0, w2f[0][0], cinit[0], 0, 0, 0);
            f32x4 acc1 = __builtin_amdgcn_mfma_f32_16x16x32_bf16(af0, w2f[1][0], cinit[1], 0, 0, 0);
            f32x4 acc2 = __builtin_amdgcn_mfma_f32_16x16x32_bf16(af0, w2f[2][0], cinit[2], 0, 0, 0);
            f32x4 acc3 = __builtin_amdgcn_mfma_f32_16x16x32_bf16(af0, w2f[3][0], cinit[3], 0, 0, 0);
            acc0 = __builtin_amdgcn_mfma_f32_16x16x32_bf16(af1, w2f[0][1], acc0, 0, 0, 0);
            acc1 = __builtin_amdgcn_mfma_f32_16x16x32_bf16(af1, w2f[1][1], acc1, 0, 0, 0);
            acc2 = __builtin_amdgcn_mfma_f32_16x16x32_bf16(af1, w2f[2][1], acc2, 0, 0, 0);
            acc3 = __builtin_amdgcn_mfma_f32_16x16x32_bf16(af1, w2f[3][1], acc3, 0, 0, 0);
            // L3: out[m] = b3 + sum_n elu(acc[m][n]) * w3[n]
            float o0 = 0.0f, o1 = 0.0f, o2 = 0.0f, o3 = 0.0f;
            o0 = fmaf(elu(acc0[0]), w3v[0], o0);
            o1 = fmaf(elu(acc0[1]), w3v[0], o1);
            o2 = fmaf(elu(acc0[2]), w3v[0], o2);
            o3 = fmaf(elu(acc0[3]), w3v[0], o3);
            o0 = fmaf(elu(acc1[0]), w3v[1], o0);
            o1 = fmaf(elu(acc1[1]), w3v[1], o1);
            o2 = fmaf(elu(acc1[2]), w3v[1], o2);
            o3 = fmaf(elu(acc1[3]), w3v[1], o3);
            o0 = fmaf(elu(acc2[0]), w3v[2], o0);
            o1 = fmaf(elu(acc2[1]), w3v[2], o1);
            o2 = fmaf(elu(acc2[2]), w3v[2], o2);
            o3 = fmaf(elu(acc2[3]), w3v[2], o3);
            o0 = fmaf(elu(acc3[0]), w3v[3], o0);
            o1 = fmaf(elu(acc3[1]), w3v[3], o1);
            o2 = fmaf(elu(acc3[2]), w3v[3], o2);
            o3 = fmaf(elu(acc3[3]), w3v[3], o3);
            // butterfly over the 16 D-columns (lanes sharing lg)
#pragma unroll
            for (int s = 1; s < 16; s <<= 1) {
                o0 += __shfl_xor(o0, s, 64);
                o1 += __shfl_xor(o1, s, 64);
                o2 += __shfl_xor(o2, s, 64);
                o3 += __shfl_xor(o3, s, 64);
            }
            if (li < 4) {
                const float val =
                    ((li == 0) ? o0 : (li == 1) ? o1 : (li == 2) ? o2 : o3) + b3v;
                const int m = eb + lg * 4 + li;  // D row = 4*lg + r
                fb[2 * swz(m >> 1) + (m & 1)] = val;
            }
        }
    }
    __syncthreads();

    // ---------------- phase 2: forward FFT-4096 of packed z, result -> bufA
    fft_stage<-1, 0>(bufB, bufA, tid);
    __syncthreads();
    fft_stage<-1, 1>(bufA, bufB, tid);
    __syncthreads();
    fft_stage<-1, 2>(bufB, bufA, tid);
    __syncthreads();

    // ---------------- phase 3: rfft unpack, multiply by g, irfft repack -> bufB
    {
        cpx w;
        {
            float ang = -TWO_PI_F * (float)tid / 8192.0f;
            __sincosf(ang, &w.y, &w.x);
        }
        const cpx wstep{0.98078528040323044913f, -0.19509032201612826785f};  // cis(-pi/16)
#pragma unroll 1
        for (int c = 0; c < 16; ++c) {
            const int k = tid + 256 * c;
            const int kk = (4096 - k) & 4095;
            const cpx Zk = bufA[swz(k)];
            const cpx Zc = cconj(bufA[swz(kk)]);
            const cpx s = cadd(Zk, Zc);
            const cpx d = csub(Zk, Zc);
            const cpx wd = cmul(w, d);
            const cpx huh{0.5f * (s.x + wd.y), 0.5f * (s.y - wd.x)};
            const cpx Zr = cconj(Zc);
            const cpx Zkc = cconj(Zk);
            const cpx s2 = cadd(Zr, Zkc);
            const cpx d2 = csub(Zr, Zkc);
            const cpx wr{-w.x, w.y};
            const cpx wd2 = cmul(wr, d2);
            const cpx huhr{0.5f * (s2.x + wd2.y), 0.5f * (s2.y - wd2.x)};
            const cpx Yk = cmul(gk[k], huh);
            const cpx Yrc = cconj(cmul(gk[4096 - k], huhr));
            const cpx E = cscale(0.5f, cadd(Yk, Yrc));
            const cpx D = cscale(0.5f, csub(Yk, Yrc));
            const cpx O = cmul(cconj(w), D);
            const cpx Zi{E.x - O.y, E.y + O.x};
            bufB[swz(k)] = Zi;
            w = cmul(w, wstep);
        }
    }
    __syncthreads();

    // ---------------- phase 4: inverse FFT-4096 (unnormalized), result -> bufA
    fft_stage<1, 0>(bufB, bufA, tid);
    __syncthreads();
    fft_stage<1, 1>(bufA, bufB, tid);
    __syncthreads();
    fft_stage<1, 2>(bufB, bufA, tid);
    __syncthreads();

    // ---------------- phase 5: unpack, scale by 1/4096, write
    const float invn = 1.0f / 4096.0f;
    cpx* orow = (cpx*)(out + (size_t)row * 8192);
#pragma unroll 1
    for (int c = 0; c < 16; ++c) {
        const int n = tid + 256 * c;
        const cpx z = bufA[swz(n)];
        orow[n] = cpx{z.x * invn, z.y * invn};
    }
}

extern "C" void kernel_launch(void* const* d_in, const int* in_sizes, int n_in,
                              void* d_out, int out_size, void* d_ws, size_t ws_size,
                              hipStream_t stream) {
    const float* u   = (const float*)d_in[0];
    const float* kin = (const float*)d_in[1];
    const float* hw1 = (const float*)d_in[2];
    const float* hb1 = (const float*)d_in[3];
    const float* hw2 = (const float*)d_in[4];
    const float* hb2 = (const float*)d_in[5];
    const float* hw3 = (const float*)d_in[6];
    const float* hb3 = (const float*)d_in[7];
    const float* gw1 = (const float*)d_in[8];
    const float* gb1 = (const float*)d_in[9];
    const float* gw2 = (const float*)d_in[10];
    const float* gb2 = (const float*)d_in[11];
    const float* gw3 = (const float*)d_in[12];
    const float* gb3 = (const float*)d_in[13];

    cpx* gk = (cpx*)d_ws;  // 4097 * 8 bytes
    gk_kernel<<<17, 256, 0, stream>>>(kin, gw1, gb1, gw2, gb2, gw3, gb3, gk);
    morp_main<<<2048, 256, 0, stream>>>(u, hw1, hb1, hw2, hb2, hw3, hb3, gk,
                                        (float*)d_out);
}